// Round 10
// baseline (100.871 us; speedup 1.0000x reference)
//
#include <hip/hip_runtime.h>
#include <math.h>

#define N_NODES 1024
#define DIM     256

typedef float f32x2 __attribute__((ext_vector_type(2)));
typedef float f32x4 __attribute__((ext_vector_type(4)));

__device__ __forceinline__ f32x2 relu2(f32x2 x) {
    return __builtin_elementwise_max(x, (f32x2)0.0f);
}

// ---------------------------------------------------------------------------
// k1 v3 (unchanged, measured-working): At[d][i] = nodes@Wa.T + b1 (transposed),
// Bt[d][i] = nodes@Wb.T. Tile 32i x 16d, grid 512 = 2 blocks/CU.
// ---------------------------------------------------------------------------
__global__ __launch_bounds__(256, 2) void k1_gemm(
    const float* __restrict__ nodes, const float* __restrict__ W1,
    const float* __restrict__ b1, float* __restrict__ At, float* __restrict__ Bt)
{
    __shared__ float nt[128][34];     // 17408 B, k-chunked nodes^T
    __shared__ f32x2 wab[DIM][17];    // 34816 B, full-k {Wa,Wb}^T

    const int t  = threadIdx.x;
    const int i0 = (blockIdx.x & 31) * 32;
    const int d0 = (blockIdx.x >> 5) * 16;

    {
        const int m = t & 15, s = t >> 4;
        const float* srcA = W1 + (d0 + s) * (2 * DIM);
        const float* srcB = srcA + DIM;
        #pragma unroll
        for (int rep = 0; rep < 4; ++rep) {
            const int k = rep * 64 + m * 4;
            float4 va = *(const float4*)(srcA + k);
            float4 vb = *(const float4*)(srcB + k);
            wab[k+0][s] = f32x2{va.x, vb.x};
            wab[k+1][s] = f32x2{va.y, vb.y};
            wab[k+2][s] = f32x2{va.z, vb.z};
            wab[k+3][s] = f32x2{va.w, vb.w};
        }
    }

    const int tx = t & 15;
    const int ty = t >> 4;
    const int sm = t & 7, ss = t >> 3;
    const float* nsrc = nodes + (i0 + ss) * DIM;

    f32x2 accA = {0.f, 0.f}, accB = {0.f, 0.f};

    for (int kc = 0; kc < DIM; kc += 128) {
        __syncthreads();
        #pragma unroll
        for (int rep = 0; rep < 4; ++rep) {
            const int k = rep * 32 + sm * 4;
            float4 v = *(const float4*)(nsrc + kc + k);
            nt[k+0][ss] = v.x; nt[k+1][ss] = v.y;
            nt[k+2][ss] = v.z; nt[k+3][ss] = v.w;
        }
        __syncthreads();

        #pragma unroll 8
        for (int k = 0; k < 128; ++k) {
            f32x2 av = *(const f32x2*)&nt[k][tx * 2];
            f32x2 wv = wab[kc + k][ty];
            f32x2 waa = __builtin_shufflevector(wv, wv, 0, 0);
            f32x2 wbb = __builtin_shufflevector(wv, wv, 1, 1);
            accA = __builtin_elementwise_fma(av, waa, accA);
            accB = __builtin_elementwise_fma(av, wbb, accB);
        }
    }

    const int d = d0 + ty;
    const int i = i0 + tx * 2;
    const float bb = b1[d];
    f32x2 oa = accA + f32x2{bb, bb};
    *(f32x2*)&At[d * N_NODES + i] = oa;
    *(f32x2*)&Bt[d * N_NODES + i] = accB;
}

// ---------------------------------------------------------------------------
// k2 v5: out[i,j] = sigmoid( sum_d relu(At[d][i]+Bt[d][j]) * w2[d] + b2 )
// LDS-BW is the bottleneck pipe (R7 analysis) -> raise intensity per LDS byte:
// 64x64 tile, 4x4 micro => (4+4)*4B per 16 elems = 2 B/elem (was 4),
// total LDS read 536 MB ~ 8-10 us at measured LDS BW.
// Grid (1024/64)^2 = 256 = 1 block/CU, 256 threads = 4 waves.
// D chunked 2x128 -> LDS 64 KB. Reads conflict-free: a = 4 addrs x16
// broadcast; b = 16 addrs x4 bcast, 2-way bank alias (free).
// Per d per thread: 2x b128 LDS read + 24 packed VALU for 16 elems.
// ---------------------------------------------------------------------------
__global__ __launch_bounds__(256) void k2_pair(
    const float* __restrict__ At, const float* __restrict__ Bt,
    const float* __restrict__ W2, const float* __restrict__ b2,
    float* __restrict__ out)
{
    __shared__ float As[128][64];   // 32 KB
    __shared__ float Bs[128][64];   // 32 KB

    const int t  = threadIdx.x;
    const int i0 = (blockIdx.x & 15) * 64;
    const int j0 = (blockIdx.x >> 4) * 64;
    const int tx = t & 15;   // j-quad: j = j0 + tx*4
    const int ty = t >> 4;   // i-quad: i = i0 + ty*4

    f32x2 acc[4][2] = {};    // [row r][col-pair c]

    for (int dc = 0; dc < DIM; dc += 128) {
        __syncthreads();   // protect previous chunk's readers
        #pragma unroll
        for (int rep = 0; rep < 8; ++rep) {
            const int flat = rep * 256 + t;      // 0..2047
            const int row  = flat >> 4;          // 0..127
            const int c4   = (flat & 15) * 4;    // 0..60
            *(float4*)&As[row][c4] = *(const float4*)(At + (dc+row) * N_NODES + i0 + c4);
            *(float4*)&Bs[row][c4] = *(const float4*)(Bt + (dc+row) * N_NODES + j0 + c4);
        }
        __syncthreads();

        #pragma unroll 4
        for (int d = 0; d < 128; ++d) {
            const float w = W2[dc + d];                    // uniform -> s_load
            f32x2 wv = {w, w};
            f32x4 a4 = *(const f32x4*)&As[d][ty * 4];      // b128
            f32x4 b4 = *(const f32x4*)&Bs[d][tx * 4];      // b128
            f32x2 b01 = __builtin_shufflevector(b4, b4, 0, 1);
            f32x2 b23 = __builtin_shufflevector(b4, b4, 2, 3);
            #pragma unroll
            for (int r = 0; r < 4; ++r) {
                f32x2 ar = { a4[r], a4[r] };               // splat (op_sel-foldable)
                acc[r][0] = __builtin_elementwise_fma(relu2(ar + b01), wv, acc[r][0]);
                acc[r][1] = __builtin_elementwise_fma(relu2(ar + b23), wv, acc[r][1]);
            }
        }
    }

    const float bb = b2[0];
    #pragma unroll
    for (int r = 0; r < 4; ++r) {
        float4 o;
        o.x = 1.0f / (1.0f + __expf(-(acc[r][0].x + bb)));
        o.y = 1.0f / (1.0f + __expf(-(acc[r][0].y + bb)));
        o.z = 1.0f / (1.0f + __expf(-(acc[r][1].x + bb)));
        o.w = 1.0f / (1.0f + __expf(-(acc[r][1].y + bb)));
        *(float4*)&out[(i0 + ty*4 + r) * N_NODES + j0 + tx*4] = o;
    }
}

extern "C" void kernel_launch(void* const* d_in, const int* in_sizes, int n_in,
                              void* d_out, int out_size, void* d_ws, size_t ws_size,
                              hipStream_t stream) {
    const float* nodes = (const float*)d_in[0];   // (1024, 256)
    const float* W1    = (const float*)d_in[1];   // (256, 512)
    const float* b1    = (const float*)d_in[2];   // (256,)
    const float* W2    = (const float*)d_in[3];   // (1, 256)
    const float* b2    = (const float*)d_in[4];   // (1,)
    float* out = (float*)d_out;                   // (1024, 1024)

    float* At = (float*)d_ws;                     // [256][1024] = 1 MB
    float* Bt = At + DIM * N_NODES;               // [256][1024] = 1 MB

    k1_gemm<<<512, 256, 0, stream>>>(nodes, W1, b1, At, Bt);
    k2_pair<<<256, 256, 0, stream>>>(At, Bt, W2, b2, out);
}

// Round 18
// 88.201 us; speedup vs baseline: 1.1436x; 1.1436x over previous
//
#include <hip/hip_runtime.h>
#include <math.h>

#define N_NODES 1024
#define DIM     256

typedef float f32x2 __attribute__((ext_vector_type(2)));
typedef _Float16 f16x2 __attribute__((ext_vector_type(2)));
typedef unsigned short ushort8 __attribute__((ext_vector_type(8)));
typedef unsigned int uint2v __attribute__((ext_vector_type(2)));

__device__ __forceinline__ f16x2 as_h2(unsigned int u) {
    union { unsigned int u; f16x2 h; } x; x.u = u; return x.h;
}
__device__ __forceinline__ unsigned int as_u32(f16x2 h) {
    union { unsigned int u; f16x2 h; } x; x.h = h; return x.u;
}
// __builtin_amdgcn_cvt_pkrtz returns __fp16x2; bit-cast to our _Float16x2.
__device__ __forceinline__ f16x2 cvt_pkrtz(float a, float b) {
    return __builtin_bit_cast(f16x2, __builtin_amdgcn_cvt_pkrtz(a, b));
}

// ---------------------------------------------------------------------------
// k1 v4: same tiling as measured k1 v3 (32i x 16d, grid 512, 2 blocks/CU),
// but outputs fp16: Ath[d][i] = (half)(nodes@Wa.T + b1), Bth[d][i] = (half)(nodes@Wb.T)
// via v_cvt_pkrtz_f16_f32. Halves k2's staging fetch and enables f16 LDS.
// ---------------------------------------------------------------------------
__global__ __launch_bounds__(256, 2) void k1_gemm(
    const float* __restrict__ nodes, const float* __restrict__ W1,
    const float* __restrict__ b1, _Float16* __restrict__ Ath, _Float16* __restrict__ Bth)
{
    __shared__ float nt[128][34];     // k-chunked nodes^T
    __shared__ f32x2 wab[DIM][17];    // full-k {Wa,Wb}^T

    const int t  = threadIdx.x;
    const int i0 = (blockIdx.x & 31) * 32;
    const int d0 = (blockIdx.x >> 5) * 16;

    {
        const int m = t & 15, s = t >> 4;
        const float* srcA = W1 + (d0 + s) * (2 * DIM);
        const float* srcB = srcA + DIM;
        #pragma unroll
        for (int rep = 0; rep < 4; ++rep) {
            const int k = rep * 64 + m * 4;
            float4 va = *(const float4*)(srcA + k);
            float4 vb = *(const float4*)(srcB + k);
            wab[k+0][s] = f32x2{va.x, vb.x};
            wab[k+1][s] = f32x2{va.y, vb.y};
            wab[k+2][s] = f32x2{va.z, vb.z};
            wab[k+3][s] = f32x2{va.w, vb.w};
        }
    }

    const int tx = t & 15;     // i pair
    const int ty = t >> 4;     // d
    const int sm = t & 7, ss = t >> 3;
    const float* nsrc = nodes + (i0 + ss) * DIM;

    f32x2 accA = {0.f, 0.f}, accB = {0.f, 0.f};

    for (int kc = 0; kc < DIM; kc += 128) {
        __syncthreads();
        #pragma unroll
        for (int rep = 0; rep < 4; ++rep) {
            const int k = rep * 32 + sm * 4;
            float4 v = *(const float4*)(nsrc + kc + k);
            nt[k+0][ss] = v.x; nt[k+1][ss] = v.y;
            nt[k+2][ss] = v.z; nt[k+3][ss] = v.w;
        }
        __syncthreads();

        #pragma unroll 8
        for (int k = 0; k < 128; ++k) {
            f32x2 av = *(const f32x2*)&nt[k][tx * 2];
            f32x2 wv = wab[kc + k][ty];
            f32x2 waa = __builtin_shufflevector(wv, wv, 0, 0);
            f32x2 wbb = __builtin_shufflevector(wv, wv, 1, 1);
            accA = __builtin_elementwise_fma(av, waa, accA);
            accB = __builtin_elementwise_fma(av, wbb, accB);
        }
    }

    const int d = d0 + ty;
    const int i = i0 + tx * 2;
    const float bb = b1[d];
    f16x2 ha = cvt_pkrtz(accA.x + bb, accA.y + bb);
    f16x2 hb = cvt_pkrtz(accB.x, accB.y);
    *(f16x2*)&Ath[d * N_NODES + i] = ha;
    *(f16x2*)&Bth[d * N_NODES + i] = hb;
}

// ---------------------------------------------------------------------------
// k2 v6: out[i,j] = sigmoid( sum_d relu(A[d][i]+B[d][j]) * w2[d] + b2 )
// Keep v4's proven occupancy (32x32 tile, grid 1024, 4 blocks/CU = 16 waves/CU)
// but halve LDS bytes/elem via fp16 d-PAIR packing + v_dot2_f32_f16:
//   As2[dp][i] = {A[2dp][i], A[2dp+1][i]} as f16x2 (u32)
// Inner loop per d-pair per 2x2 micro: 2x ds_read_b64 (16B for 8 d-elems =
// 2 B/elem, was 4) + 1 broadcast w-read + 4 pk_add + 4 pk_max + 4 fdot2
// (f32 accum). Full 256-d slab in LDS (~35 KB) -> ONE stage, ONE barrier.
// Pad 34 u32/row: stage writes 2-way max, inner reads conflict-free.
// ---------------------------------------------------------------------------
__global__ __launch_bounds__(256, 4) void k2_pair(
    const _Float16* __restrict__ Ath, const _Float16* __restrict__ Bth,
    const float* __restrict__ W2, const float* __restrict__ b2,
    float* __restrict__ out)
{
    __shared__ unsigned int As2[128 * 34];   // 17408 B
    __shared__ unsigned int Bs2[128 * 34];   // 17408 B
    __shared__ unsigned int w2s[128];        // 512 B

    const int t  = threadIdx.x;
    const int i0 = (blockIdx.x & 31) * 32;
    const int j0 = (blockIdx.x >> 5) * 32;

    if (t < 128) {
        f16x2 wp = cvt_pkrtz(W2[2*t], W2[2*t + 1]);
        w2s[t] = as_u32(wp);
    }

    // ---- stage: interleave d-row pairs into packed u32 (one pass, A and B)
    {
        const int dp = t >> 1;              // 0..127
        const int ih = (t & 1) * 16;        // 0 or 16
        const int base = dp * 34 + ih;

        const _Float16* ra0 = Ath + (2*dp) * N_NODES + i0 + ih;
        const _Float16* ra1 = ra0 + N_NODES;
        ushort8 al0 = *(const ushort8*)(ra0);
        ushort8 al1 = *(const ushort8*)(ra0 + 8);
        ushort8 ah0 = *(const ushort8*)(ra1);
        ushort8 ah1 = *(const ushort8*)(ra1 + 8);

        const _Float16* rb0 = Bth + (2*dp) * N_NODES + j0 + ih;
        const _Float16* rb1 = rb0 + N_NODES;
        ushort8 bl0 = *(const ushort8*)(rb0);
        ushort8 bl1 = *(const ushort8*)(rb0 + 8);
        ushort8 bh0 = *(const ushort8*)(rb1);
        ushort8 bh1 = *(const ushort8*)(rb1 + 8);

        unsigned int pa[16], pb[16];
        #pragma unroll
        for (int k = 0; k < 8; ++k) {
            pa[k]   = (unsigned int)al0[k] | ((unsigned int)ah0[k] << 16);
            pa[k+8] = (unsigned int)al1[k] | ((unsigned int)ah1[k] << 16);
            pb[k]   = (unsigned int)bl0[k] | ((unsigned int)bh0[k] << 16);
            pb[k+8] = (unsigned int)bl1[k] | ((unsigned int)bh1[k] << 16);
        }
        #pragma unroll
        for (int k = 0; k < 16; k += 2) {
            *(uint2v*)&As2[base + k] = uint2v{pa[k], pa[k+1]};
            *(uint2v*)&Bs2[base + k] = uint2v{pb[k], pb[k+1]};
        }
    }
    __syncthreads();

    const int tx = t & 15;   // j pair: j = j0 + tx*2
    const int ty = t >> 4;   // i pair: i = i0 + ty*2
    float acc00 = 0.f, acc01 = 0.f, acc10 = 0.f, acc11 = 0.f;

    const unsigned int* pa = As2 + ty * 2;
    const unsigned int* pb = Bs2 + tx * 2;
    const f16x2 hz = (f16x2)(_Float16)0.0f;

    #pragma unroll 8
    for (int dp = 0; dp < 128; ++dp) {
        uint2v av = *(const uint2v*)(pa + dp * 34);   // {pair(i), pair(i+1)}
        uint2v bv = *(const uint2v*)(pb + dp * 34);   // {pair(j), pair(j+1)}
        f16x2 wp = as_h2(w2s[dp]);
        f16x2 a0 = as_h2(av[0]), a1 = as_h2(av[1]);
        f16x2 b0 = as_h2(bv[0]), b1v = as_h2(bv[1]);

        f16x2 h;
        h = __builtin_elementwise_max(a0 + b0,  hz);
        acc00 = __builtin_amdgcn_fdot2(h, wp, acc00, false);
        h = __builtin_elementwise_max(a0 + b1v, hz);
        acc01 = __builtin_amdgcn_fdot2(h, wp, acc01, false);
        h = __builtin_elementwise_max(a1 + b0,  hz);
        acc10 = __builtin_amdgcn_fdot2(h, wp, acc10, false);
        h = __builtin_elementwise_max(a1 + b1v, hz);
        acc11 = __builtin_amdgcn_fdot2(h, wp, acc11, false);
    }

    const float bb = b2[0];
    float2 o0, o1;
    o0.x = 1.0f / (1.0f + __expf(-(acc00 + bb)));
    o0.y = 1.0f / (1.0f + __expf(-(acc01 + bb)));
    o1.x = 1.0f / (1.0f + __expf(-(acc10 + bb)));
    o1.y = 1.0f / (1.0f + __expf(-(acc11 + bb)));

    const int r = i0 + ty * 2;
    const int c = j0 + tx * 2;
    *(float2*)&out[(r    ) * N_NODES + c] = o0;
    *(float2*)&out[(r + 1) * N_NODES + c] = o1;
}

extern "C" void kernel_launch(void* const* d_in, const int* in_sizes, int n_in,
                              void* d_out, int out_size, void* d_ws, size_t ws_size,
                              hipStream_t stream) {
    const float* nodes = (const float*)d_in[0];   // (1024, 256)
    const float* W1    = (const float*)d_in[1];   // (256, 512)
    const float* b1    = (const float*)d_in[2];   // (256,)
    const float* W2    = (const float*)d_in[3];   // (1, 256)
    const float* b2    = (const float*)d_in[4];   // (1,)
    float* out = (float*)d_out;                   // (1024, 1024)

    _Float16* Ath = (_Float16*)d_ws;              // [256][1024] f16 = 512 KB
    _Float16* Bth = Ath + DIM * N_NODES;          // [256][1024] f16 = 512 KB

    k1_gemm<<<512,  256, 0, stream>>>(nodes, W1, b1, Ath, Bth);
    k2_pair<<<1024, 256, 0, stream>>>(Ath, Bth, W2, b2, out);
}